// Round 3
// baseline (225.132 us; speedup 1.0000x reference)
//
#include <hip/hip_runtime.h>
#include <hip/hip_bf16.h>

typedef __bf16 bf16_t;
typedef __bf16 bf16x8 __attribute__((ext_vector_type(8)));
typedef float  f32x4  __attribute__((ext_vector_type(4)));

#define T_LEN 200
#define D_DIM 256
#define NTILE 13          // ceil(200/16)

__device__ __forceinline__ float fast_tanh(float x) {
    float e = __expf(2.0f * x);
    return 1.0f - 2.0f / (e + 1.0f);
}

// ---------------------------------------------------------------------------
// Kernel 1: qpart[b][d] = sum_{k<256} Q[b][k] * W1[d][k]   (f32, exact)
// Written into d_out (read back by kernel 2 before it overwrites with result).
// ---------------------------------------------------------------------------
__global__ __launch_bounds__(256) void qpart_kernel(
    const float* __restrict__ Q, const float* __restrict__ W1,
    float* __restrict__ Out)
{
    __shared__ float qs[8][256];
    const int tid = threadIdx.x;
    const int b0  = blockIdx.x * 8;
    for (int idx = tid; idx < 8 * 256; idx += 256)
        qs[idx >> 8][idx & 255] = Q[(size_t)(b0 + (idx >> 8)) * 256 + (idx & 255)];
    __syncthreads();
    float acc[8];
    #pragma unroll
    for (int i = 0; i < 8; ++i) acc[i] = 0.f;
    const f32x4* Wv = (const f32x4*)(W1 + (size_t)tid * 512);
    #pragma unroll 4
    for (int k4 = 0; k4 < 64; ++k4) {
        f32x4 w = Wv[k4];
        #pragma unroll
        for (int bb = 0; bb < 8; ++bb) {
            f32x4 qv = *(const f32x4*)&qs[bb][k4 * 4];
            acc[bb] += qv[0]*w[0] + qv[1]*w[1] + qv[2]*w[2] + qv[3]*w[3];
        }
    }
    #pragma unroll
    for (int bb = 0; bb < 8; ++bb)
        Out[(size_t)(b0 + bb) * 256 + tid] = acc[bb];
}

// ---------------------------------------------------------------------------
// Kernel 2: one batch per block, three decoupled phases.
//  P1: stream 13 ub tiles (triple-buffered LDS bf16), MFMA vs register-held
//      W1b fragments, tanh, per-wave score partials -> atomicAdd score_lds.
//      The per-tile barrier is ONLY a staging fence; nothing consumes after.
//  P2: p = exp(masked score) (no-max softmax: |s| <= ||W2||_1 ~ 13), denom.
//  P3: PV straight from global f32 (L2/L3-hot: just streamed in P1),
//      coalesced float2 column reads, 4-way t-split, LDS combine.
// ---------------------------------------------------------------------------
__global__ __launch_bounds__(512, 4) void attn_main_kernel(
    const float* __restrict__ U,     // [B,200,256]
    const int*   __restrict__ Mask,  // [B,200]
    const float* __restrict__ W1,    // [256,512]
    const float* __restrict__ W2,    // [256]
    float* __restrict__ Out)         // [B,256]; holds qpart on entry
{
    __shared__ bf16_t ubt[3][16 * 256];        // 24 KB, XOR-swizzled
    __shared__ float score_lds[208];
    __shared__ float p_lds[208];
    __shared__ float out_lds[4][256];
    __shared__ float l_lds;

    const int tid  = threadIdx.x;
    const int lane = tid & 63;
    const int wv   = tid >> 6;   // wave 0..7
    const int lr   = lane & 15;
    const int lg   = lane >> 4;
    const int b    = blockIdx.x;

    // --- W1b B-fragments in registers (whole kernel): 64 VGPR ---
    bf16x8 bq[2][8];
    float  w2v[2];
    #pragma unroll
    for (int n = 0; n < 2; ++n) {
        const int d = wv * 32 + n * 16 + lr;
        const float* wrow = W1 + (size_t)d * 512 + 256;
        #pragma unroll
        for (int kk = 0; kk < 8; ++kk) {
            const float* s = wrow + kk * 32 + lg * 8;
            f32x4 lo = *(const f32x4*)s;
            f32x4 hi = *(const f32x4*)(s + 4);
            bf16x8 v;
            v[0]=(bf16_t)lo[0]; v[1]=(bf16_t)lo[1]; v[2]=(bf16_t)lo[2]; v[3]=(bf16_t)lo[3];
            v[4]=(bf16_t)hi[0]; v[5]=(bf16_t)hi[1]; v[6]=(bf16_t)hi[2]; v[7]=(bf16_t)hi[3];
            bq[n][kk] = v;
        }
        w2v[n] = W2[d];
    }

    const float* Ub = U + (size_t)b * (T_LEN * D_DIM);

    float qp[2];
    #pragma unroll
    for (int n = 0; n < 2; ++n)
        qp[n] = Out[(size_t)b * 256 + wv * 32 + n * 16 + lr];  // qpart from k1

    if (tid < 208) score_lds[tid] = 0.f;
    if (tid == 0)  l_lds = 0.f;

    // staging geometry: thread -> (row tid>>5, 8 cols from (tid&31)*8)
    const int srow = tid >> 5;
    const int scol = (tid & 31) * 8;
    const unsigned swoff = (unsigned)srow * 512
                         + (((unsigned)scol * 2) ^ (((unsigned)srow & 7) << 4));

    // stage tile 0 -> buf 0 (all 16 rows valid)
    {
        const float* src = Ub + (size_t)srow * 256 + scol;
        f32x4 g0 = *(const f32x4*)src;
        f32x4 g1 = *(const f32x4*)(src + 4);
        bf16x8 v;
        v[0]=(bf16_t)g0[0]; v[1]=(bf16_t)g0[1]; v[2]=(bf16_t)g0[2]; v[3]=(bf16_t)g0[3];
        v[4]=(bf16_t)g1[0]; v[5]=(bf16_t)g1[1]; v[6]=(bf16_t)g1[2]; v[7]=(bf16_t)g1[3];
        *(bf16x8*)((char*)&ubt[0][0] + swoff) = v;
    }
    __syncthreads();

    // ---------------- Phase 1: scores only ----------------
    for (int it = 0; it < NTILE; ++it) {
        char* const bcur = (char*)&ubt[it % 3][0];
        char* const bnxt = (char*)&ubt[(it + 1) % 3][0];

        // issue next-tile global loads early
        f32x4 g0 = {0.f,0.f,0.f,0.f}, g1 = {0.f,0.f,0.f,0.f};
        bool stage_w = false;
        if (it + 1 < NTILE) {
            const int t = (it + 1) * 16 + srow;
            if (t < T_LEN) {
                const float* src = Ub + (size_t)t * 256 + scol;
                g0 = *(const f32x4*)src;
                g1 = *(const f32x4*)(src + 4);
                stage_w = true;
            }
        }

        // MFMA: rows it*16.., this wave's 32 cols, K=256
        f32x4 acc0 = {0.f,0.f,0.f,0.f}, acc1 = {0.f,0.f,0.f,0.f};
        #pragma unroll
        for (int kk = 0; kk < 8; ++kk) {
            const unsigned kb   = (unsigned)(kk * 64 + lg * 16);
            const unsigned aoff = (unsigned)lr * 512
                                + (kb ^ (((unsigned)lr & 7) << 4));
            bf16x8 a = *(const bf16x8*)(bcur + aoff);
            acc0 = __builtin_amdgcn_mfma_f32_16x16x32_bf16(a, bq[0][kk], acc0, 0, 0, 0);
            acc1 = __builtin_amdgcn_mfma_f32_16x16x32_bf16(a, bq[1][kk], acc1, 0, 0, 0);
        }

        // write staged next tile (other buffer)
        if (stage_w) {
            bf16x8 v;
            v[0]=(bf16_t)g0[0]; v[1]=(bf16_t)g0[1]; v[2]=(bf16_t)g0[2]; v[3]=(bf16_t)g0[3];
            v[4]=(bf16_t)g1[0]; v[5]=(bf16_t)g1[1]; v[6]=(bf16_t)g1[2]; v[7]=(bf16_t)g1[3];
            *(bf16x8*)(bnxt + swoff) = v;
        }

        // partial scores over this wave's 32 cols; row t = it*16 + lg*4 + r
        float sp[4];
        #pragma unroll
        for (int r = 0; r < 4; ++r) {
            float h0 = fast_tanh(acc0[r] + qp[0]);
            float h1 = fast_tanh(acc1[r] + qp[1]);
            sp[r] = h0 * w2v[0] + h1 * w2v[1];
        }
        #pragma unroll
        for (int r = 0; r < 4; ++r) {
            sp[r] += __shfl_xor(sp[r], 1);
            sp[r] += __shfl_xor(sp[r], 2);
            sp[r] += __shfl_xor(sp[r], 4);
            sp[r] += __shfl_xor(sp[r], 8);
        }
        if (lr == 0) {
            #pragma unroll
            for (int r = 0; r < 4; ++r)
                atomicAdd(&score_lds[it * 16 + lg * 4 + r], sp[r]);
        }

        __syncthreads();   // staging fence only — nothing consumes scores here
    }

    // ---------------- Phase 2: p = exp(masked s), denom ----------------
    {
        float p = 0.f;
        if (tid < T_LEN)
            p = Mask[(size_t)b * T_LEN + tid] ? 1.0f : __expf(score_lds[tid]);
        if (tid < 208) p_lds[tid] = p;   // 200..207 stay 0
        float ps = p;
        ps += __shfl_xor(ps, 1);
        ps += __shfl_xor(ps, 2);
        ps += __shfl_xor(ps, 4);
        ps += __shfl_xor(ps, 8);
        ps += __shfl_xor(ps, 16);
        ps += __shfl_xor(ps, 32);
        if (lane == 0 && ps != 0.f) atomicAdd(&l_lds, ps);
    }
    __syncthreads();

    // ---------------- Phase 3: PV from global (L2/L3-hot) ----------------
    {
        const int dp = tid & 127;   // d-pair: cols {2dp, 2dp+1}
        const int jg = tid >> 7;    // t-quarter: [jg*50, jg*50+50)
        float o0 = 0.f, o1 = 0.f;
        const float* Up = Ub + (size_t)(jg * 50) * 256 + dp * 2;
        #pragma unroll 5
        for (int i = 0; i < 50; ++i) {
            const float p = p_lds[jg * 50 + i];
            const float2 u = *(const float2*)(Up + (size_t)i * 256);
            o0 += p * u.x;
            o1 += p * u.y;
        }
        out_lds[jg][dp * 2]     = o0;
        out_lds[jg][dp * 2 + 1] = o1;
    }
    __syncthreads();

    if (tid < 256) {
        const float o = out_lds[0][tid] + out_lds[1][tid]
                      + out_lds[2][tid] + out_lds[3][tid];
        Out[(size_t)b * 256 + tid] = o / l_lds;
    }
}

extern "C" void kernel_launch(void* const* d_in, const int* in_sizes, int n_in,
                              void* d_out, int out_size, void* d_ws, size_t ws_size,
                              hipStream_t stream)
{
    const float* Q  = (const float*)d_in[0];
    const float* U  = (const float*)d_in[1];
    const int*   Mk = (const int*)d_in[2];
    const float* W1 = (const float*)d_in[3];
    const float* W2 = (const float*)d_in[4];
    float* Out = (float*)d_out;
    const int B = in_sizes[0] / D_DIM;   // 2048

    qpart_kernel<<<dim3(B / 8), dim3(256), 0, stream>>>(Q, W1, Out);
    attn_main_kernel<<<dim3(B), dim3(512), 0, stream>>>(U, Mk, W1, W2, Out);
}

// Round 4
// 223.268 us; speedup vs baseline: 1.0083x; 1.0083x over previous
//
#include <hip/hip_runtime.h>
#include <hip/hip_bf16.h>

typedef __bf16 bf16_t;
typedef __bf16 bf16x4_t __attribute__((ext_vector_type(4)));
typedef __bf16 bf16x8  __attribute__((ext_vector_type(8)));
typedef float  f32x4   __attribute__((ext_vector_type(4)));

#define T_LEN 200
#define D_DIM 256

__device__ __forceinline__ float fast_tanh(float x) {
    float e = __expf(2.0f * x);
    return 1.0f - 2.0f / (e + 1.0f);
}

// ---------------------------------------------------------------------------
// Kernel 1a: qpart[b][d] = sum_k Q[b][k] * W1[d][k]  (f32) -> d_out (scratch)
// ---------------------------------------------------------------------------
__global__ __launch_bounds__(256) void qpart_kernel(
    const float* __restrict__ Q, const float* __restrict__ W1,
    float* __restrict__ Out)
{
    __shared__ float qs[8][256];
    const int tid = threadIdx.x;
    const int b0  = blockIdx.x * 8;
    for (int idx = tid; idx < 8 * 256; idx += 256)
        qs[idx >> 8][idx & 255] = Q[(size_t)(b0 + (idx >> 8)) * 256 + (idx & 255)];
    __syncthreads();
    float acc[8];
    #pragma unroll
    for (int i = 0; i < 8; ++i) acc[i] = 0.f;
    const f32x4* Wv = (const f32x4*)(W1 + (size_t)tid * 512);
    #pragma unroll 4
    for (int k4 = 0; k4 < 64; ++k4) {
        f32x4 w = Wv[k4];
        #pragma unroll
        for (int bb = 0; bb < 8; ++bb) {
            f32x4 qv = *(const f32x4*)&qs[bb][k4 * 4];
            acc[bb] += qv[0]*w[0] + qv[1]*w[1] + qv[2]*w[2] + qv[3]*w[3];
        }
    }
    #pragma unroll
    for (int bb = 0; bb < 8; ++bb)
        Out[(size_t)(b0 + bb) * 256 + tid] = acc[bb];
}

// ---------------------------------------------------------------------------
// Kernel 1b: W1b (= W1[:,256:512]) -> bf16, row-major [256][256] in ws.
// ---------------------------------------------------------------------------
__global__ __launch_bounds__(256) void convw_kernel(
    const float* __restrict__ W1, bf16_t* __restrict__ bfW)
{
    const int d = blockIdx.x;           // 0..255
    const int k = threadIdx.x;          // 0..255
    bfW[(size_t)d * 256 + k] = (bf16_t)W1[(size_t)d * 512 + 256 + k];
}

// ---------------------------------------------------------------------------
// Kernel 2: one (batch, half) per block.
//   A: stage rows -> bf16 LDS (XOR-swizzled), ZERO barriers (wave-owned rows)
//   B: per-wave m-tile loop: MFMA vs register W1b frags, tanh, score atomics,
//      ZERO barriers
//   C: p = exp(masked s) (no-max softmax, |s|<=||W2||_1~13), denom
//   D: PV from LDS bf16, partial numerator -> ws; combine kernel divides.
// SPLIT=false fallback (no ws): whole batch in one block, writes Out directly.
// ---------------------------------------------------------------------------
template<bool SPLIT>
__global__ __launch_bounds__(512, SPLIT ? 4 : 2) void attn_fused_kernel(
    const float* __restrict__ U,      // [B,200,256]
    const int*   __restrict__ Mask,   // [B,200]
    const float* __restrict__ W1,     // [256,512] (fallback bq source)
    const float* __restrict__ W2,     // [256]
    const bf16_t* __restrict__ bfW,   // [256][256] bf16 W1b (SPLIT only)
    float* Out,                       // qpart on entry; !SPLIT: final out
    float* __restrict__ WsNum,        // [grid][256] (SPLIT)
    float* __restrict__ WsL)          // [grid]      (SPLIT)
{
    constexpr int MAXT = SPLIT ? 7 : 13;
    __shared__ bf16_t tiles[MAXT * 16 * 256];   // 56KB / 104KB
    __shared__ float score_lds[MAXT * 16];
    __shared__ float p_lds[MAXT * 16];
    __shared__ float out_lds[4][256];
    __shared__ float l_lds;

    const int tid  = threadIdx.x;
    const int lane = tid & 63;
    const int wv   = tid >> 6;
    const int lr   = lane & 15;
    const int lg   = lane >> 4;

    int b, t0, ntile;
    if (SPLIT) {
        b = blockIdx.x >> 1;
        const int h = blockIdx.x & 1;
        t0 = h ? 112 : 0;
        ntile = h ? 6 : 7;      // half1 stages 96 rows (88 real + 8 zero)
    } else {
        b = blockIdx.x; t0 = 0; ntile = 13;   // 208 rows (200 real + 8 zero)
    }
    const int rows = ntile * 16;
    char* const tbase = (char*)tiles;

    if (tid < rows) score_lds[tid] = 0.f;
    if (tid == 0)   l_lds = 0.f;

    // ---- Phase A: stage rows (wave-owned, no barriers) ----
    {
        const float* Ub = U + (size_t)b * (T_LEN * D_DIM);
        #pragma unroll 2
        for (int r = wv; r < rows; r += 8) {
            const int t = t0 + r;
            bf16x4_t v;
            v[0] = (bf16_t)0.f; v[1] = (bf16_t)0.f;
            v[2] = (bf16_t)0.f; v[3] = (bf16_t)0.f;
            if (t < T_LEN) {
                f32x4 g = *(const f32x4*)(Ub + (size_t)t * 256 + lane * 4);
                v[0] = (bf16_t)g[0]; v[1] = (bf16_t)g[1];
                v[2] = (bf16_t)g[2]; v[3] = (bf16_t)g[3];
            }
            *(bf16x4_t*)(tbase + r * 512 + ((lane * 8) ^ ((r & 7) << 4))) = v;
        }
    }

    // ---- B-fragments (32 cols/wave) + W2 while staging loads land ----
    bf16x8 bq[2][8];
    float  w2v[2];
    #pragma unroll
    for (int n = 0; n < 2; ++n) {
        const int d = wv * 32 + n * 16 + lr;
        if (SPLIT) {
            #pragma unroll
            for (int kk = 0; kk < 8; ++kk)
                bq[n][kk] = *(const bf16x8*)(bfW + (size_t)d * 256 + kk * 32 + lg * 8);
        } else {
            const float* wrow = W1 + (size_t)d * 512 + 256;
            #pragma unroll
            for (int kk = 0; kk < 8; ++kk) {
                const float* s = wrow + kk * 32 + lg * 8;
                f32x4 lo = *(const f32x4*)s;
                f32x4 hi = *(const f32x4*)(s + 4);
                bf16x8 v;
                v[0]=(bf16_t)lo[0]; v[1]=(bf16_t)lo[1]; v[2]=(bf16_t)lo[2]; v[3]=(bf16_t)lo[3];
                v[4]=(bf16_t)hi[0]; v[5]=(bf16_t)hi[1]; v[6]=(bf16_t)hi[2]; v[7]=(bf16_t)hi[3];
                bq[n][kk] = v;
            }
        }
        w2v[n] = W2[d];
    }
    float qp[2];
    #pragma unroll
    for (int n = 0; n < 2; ++n)
        qp[n] = Out[(size_t)b * 256 + wv * 32 + n * 16 + lr];

    __syncthreads();   // staged tiles + zeroed score visible

    // ---- Phase B: all m-tiles, no barriers ----
    for (int mt = 0; mt < ntile; ++mt) {
        f32x4 acc0 = {0.f,0.f,0.f,0.f}, acc1 = {0.f,0.f,0.f,0.f};
        const int rbase = mt * 16 + lr;
        #pragma unroll
        for (int kk = 0; kk < 8; ++kk) {
            const unsigned aoff = (unsigned)rbase * 512
                + (((unsigned)(kk * 64 + lg * 16)) ^ (((unsigned)lr & 7) << 4));
            bf16x8 a = *(const bf16x8*)(tbase + aoff);
            acc0 = __builtin_amdgcn_mfma_f32_16x16x32_bf16(a, bq[0][kk], acc0, 0, 0, 0);
            acc1 = __builtin_amdgcn_mfma_f32_16x16x32_bf16(a, bq[1][kk], acc1, 0, 0, 0);
        }
        float sp[4];
        #pragma unroll
        for (int r = 0; r < 4; ++r) {
            float h0 = fast_tanh(acc0[r] + qp[0]);
            float h1 = fast_tanh(acc1[r] + qp[1]);
            sp[r] = h0 * w2v[0] + h1 * w2v[1];
        }
        #pragma unroll
        for (int r = 0; r < 4; ++r) {
            sp[r] += __shfl_xor(sp[r], 1);
            sp[r] += __shfl_xor(sp[r], 2);
            sp[r] += __shfl_xor(sp[r], 4);
            sp[r] += __shfl_xor(sp[r], 8);
        }
        if (lr == 0) {
            #pragma unroll
            for (int r = 0; r < 4; ++r)
                atomicAdd(&score_lds[mt * 16 + lg * 4 + r], sp[r]);
        }
    }
    __syncthreads();   // scores complete

    // ---- Phase C: p = exp(masked s), local denom ----
    {
        float p = 0.f;
        const int t = t0 + tid;
        if (tid < rows && t < T_LEN)
            p = Mask[(size_t)b * T_LEN + t] ? 1.0f : __expf(score_lds[tid]);
        if (tid < rows) p_lds[tid] = p;
        float ps = p;
        ps += __shfl_xor(ps, 1);
        ps += __shfl_xor(ps, 2);
        ps += __shfl_xor(ps, 4);
        ps += __shfl_xor(ps, 8);
        ps += __shfl_xor(ps, 16);
        ps += __shfl_xor(ps, 32);
        if (lane == 0 && ps != 0.f) atomicAdd(&l_lds, ps);
    }
    __syncthreads();   // p, l ready

    // ---- Phase D: PV from LDS bf16 ----
    {
        const int dp = tid & 127;   // bf16 pair {2dp, 2dp+1}
        const int jg = tid >> 7;
        const int qr = rows >> 2;
        float o0 = 0.f, o1 = 0.f;
        for (int i = 0; i < qr; ++i) {
            const int j = jg * qr + i;
            const float p = p_lds[j];
            const unsigned w = *(const unsigned*)(tbase + j * 512
                             + (((unsigned)(dp * 4)) ^ (((unsigned)j & 7) << 4)));
            o0 += p * __builtin_bit_cast(float, w << 16);
            o1 += p * __builtin_bit_cast(float, w & 0xffff0000u);
        }
        out_lds[jg][dp * 2]     = o0;
        out_lds[jg][dp * 2 + 1] = o1;
    }
    __syncthreads();

    if (tid < 256) {
        const float num = out_lds[0][tid] + out_lds[1][tid]
                        + out_lds[2][tid] + out_lds[3][tid];
        if (SPLIT) WsNum[(size_t)blockIdx.x * 256 + tid] = num;
        else       Out[(size_t)b * 256 + tid] = num / l_lds;
    }
    if (SPLIT && tid == 0) WsL[blockIdx.x] = l_lds;
}

// ---------------------------------------------------------------------------
// Kernel 3: out[b][d] = (n0 + n1) / (l0 + l1)
// ---------------------------------------------------------------------------
__global__ __launch_bounds__(256) void combine_kernel(
    const float* __restrict__ WsNum, const float* __restrict__ WsL,
    float* __restrict__ Out)
{
    const int b = blockIdx.x, tid = threadIdx.x;
    const float n = WsNum[(size_t)(2 * b) * 256 + tid]
                  + WsNum[(size_t)(2 * b + 1) * 256 + tid];
    const float l = WsL[2 * b] + WsL[2 * b + 1];
    Out[(size_t)b * 256 + tid] = n / l;
}

extern "C" void kernel_launch(void* const* d_in, const int* in_sizes, int n_in,
                              void* d_out, int out_size, void* d_ws, size_t ws_size,
                              hipStream_t stream)
{
    const float* Q  = (const float*)d_in[0];
    const float* U  = (const float*)d_in[1];
    const int*   Mk = (const int*)d_in[2];
    const float* W1 = (const float*)d_in[3];
    const float* W2 = (const float*)d_in[4];
    float* Out = (float*)d_out;
    const int B = in_sizes[0] / D_DIM;   // 2048

    qpart_kernel<<<dim3(B / 8), dim3(256), 0, stream>>>(Q, W1, Out);

    const size_t nblk = (size_t)B * 2;
    const size_t need = nblk * 256 * 4      // WsNum
                      + nblk * 4            // WsL
                      + 256 * 256 * 2;      // bfW
    if (ws_size >= need) {
        float*  wsn = (float*)d_ws;
        float*  wsl = wsn + nblk * 256;
        bf16_t* bfw = (bf16_t*)(wsl + nblk);
        convw_kernel<<<dim3(256), dim3(256), 0, stream>>>(W1, bfw);
        attn_fused_kernel<true><<<dim3((unsigned)nblk), dim3(512), 0, stream>>>(
            U, Mk, W1, W2, bfw, Out, wsn, wsl);
        combine_kernel<<<dim3(B), dim3(256), 0, stream>>>(wsn, wsl, Out);
    } else {
        attn_fused_kernel<false><<<dim3(B), dim3(512), 0, stream>>>(
            U, Mk, W1, W2, nullptr, Out, nullptr, nullptr);
    }
}